// Round 6
// baseline (324.488 us; speedup 1.0000x reference)
//
#include <hip/hip_runtime.h>
#include <cstdint>
#include <cstddef>

typedef unsigned short u16;
typedef unsigned int u32;
typedef __bf16 bf16x8 __attribute__((ext_vector_type(8)));
typedef float f32x4 __attribute__((ext_vector_type(4)));
typedef float f32x16 __attribute__((ext_vector_type(16)));

__device__ __forceinline__ u16 f2bf(float f) {
  unsigned u = __builtin_bit_cast(unsigned, f);
  return (u16)((u + 0x7FFFu + ((u >> 16) & 1u)) >> 16);
}

// native pack: compiler emits v_cvt_pk_bf16_f32
__device__ __forceinline__ u32 pk2bf(float lo, float hi) {
  union { __bf16 h[2]; u32 u; } t;
  t.h[0] = (__bf16)lo; t.h[1] = (__bf16)hi;
  return t.u;
}

__device__ __forceinline__ void gl_lds16(const void* g, void* l) {
  __builtin_amdgcn_global_load_lds(
      (const __attribute__((address_space(1))) unsigned int*)g,
      (__attribute__((address_space(3))) unsigned int*)l,
      16, 0, 0);
}

// fp32 -> bf16 cast, 4 elems/thread
__global__ void cast4_kernel(const float* __restrict__ in, u16* __restrict__ out, int n4) {
  int i = blockIdx.x * blockDim.x + threadIdx.x;
  if (i < n4) {
    float4 v = reinterpret_cast<const float4*>(in)[i];
    ushort4 o;
    o.x = f2bf(v.x); o.y = f2bf(v.y); o.z = f2bf(v.z); o.w = f2bf(v.w);
    reinterpret_cast<ushort4*>(out)[i] = o;
  }
}

// C = A(MxK) * B^T(NxK), bf16 operands, fp32 accum. 128x128 tile, BK=32.
template <int EPI>
__global__ __launch_bounds__(256)
void gemm_bt_kernel(const u16* __restrict__ A, const u16* __restrict__ Bw,
                    const float* __restrict__ bias,
                    u16* __restrict__ oq, u16* __restrict__ ok, u16* __restrict__ ovT,
                    float* __restrict__ ofp, int M, int N, int K) {
  __shared__ __align__(16) u16 Als[2][128 * 32];
  __shared__ __align__(16) u16 Bls[2][128 * 32];

  const int tid = threadIdx.x;
  const int lane = tid & 63;
  const int w = tid >> 6, wr = w >> 1, wc = w & 1;
  const int lr = lane & 15, lk = lane >> 4;
  const int brow = blockIdx.y * 128, bcol = blockIdx.x * 128;

  const int srow = tid >> 2;
  const int scol = (tid & 3) << 3;
  const u16* ga = A + (size_t)(brow + srow) * K + scol;
  const u16* gb = Bw + (size_t)(bcol + srow) * K + scol;

  f32x4 acc[4][4] = {};

  auto stage = [&](int buf, int kt) {
    const u16* a0 = ga + kt * 32;
    const u16* b0 = gb + kt * 32;
    gl_lds16(a0,             &Als[buf][tid * 8]);
    gl_lds16(a0 + 64 * K,    &Als[buf][2048 + tid * 8]);
    gl_lds16(b0,             &Bls[buf][tid * 8]);
    gl_lds16(b0 + 64 * K,    &Bls[buf][2048 + tid * 8]);
  };

  stage(0, 0);
  __syncthreads();

  const int nt = K >> 5;
  int cur = 0;
  for (int t = 0; t < nt; ++t) {
    if (t + 1 < nt) stage(cur ^ 1, t + 1);
    bf16x8 af[4], bfr[4];
#pragma unroll
    for (int m = 0; m < 4; ++m)
      af[m] = *reinterpret_cast<const bf16x8*>(&Als[cur][(wr * 64 + m * 16 + lr) * 32 + lk * 8]);
#pragma unroll
    for (int n = 0; n < 4; ++n)
      bfr[n] = *reinterpret_cast<const bf16x8*>(&Bls[cur][(wc * 64 + n * 16 + lr) * 32 + lk * 8]);
#pragma unroll
    for (int m = 0; m < 4; ++m)
#pragma unroll
      for (int n = 0; n < 4; ++n)
        acc[m][n] = __builtin_amdgcn_mfma_f32_16x16x32_bf16(af[m], bfr[n], acc[m][n], 0, 0, 0);
    __syncthreads();
    cur ^= 1;
  }

  if (EPI == 0) {
    const int three = bcol >> 10;
#pragma unroll
    for (int n = 0; n < 4; ++n) {
      const int c = bcol + wc * 64 + n * 16 + lr;
      const float bv = bias[c];
      const int cc = c & 1023, h = cc >> 6, hd = cc & 63;
#pragma unroll
      for (int m = 0; m < 4; ++m) {
        const int r0 = brow + wr * 64 + m * 16 + lk * 4;
        const int b = r0 >> 11;
        const int s0 = r0 & 2047;
        if (three == 2) {
          ushort4 pkv;
          pkv.x = f2bf(acc[m][n][0] + bv);
          pkv.y = f2bf(acc[m][n][1] + bv);
          pkv.z = f2bf(acc[m][n][2] + bv);
          pkv.w = f2bf(acc[m][n][3] + bv);
          *reinterpret_cast<ushort4*>(&ovT[((size_t)(b * 16 + h) * 64 + hd) * 2048 + s0]) = pkv;
        } else {
          u16* dst = (three == 0) ? oq : ok;
          // q prescale: SCALE * log2(e) so attention uses raw v_exp (2^x)
          const float sc = (three == 0) ? 0.03125f * 1.44269504089f : 1.0f;
#pragma unroll
          for (int j = 0; j < 4; ++j)
            dst[((size_t)(b * 16 + h) * 2048 + (s0 + j)) * 64 + hd] = f2bf((acc[m][n][j] + bv) * sc);
        }
      }
    }
  } else {
#pragma unroll
    for (int n = 0; n < 4; ++n) {
      const int c = bcol + wc * 64 + n * 16 + lr;
      const float bv = bias[c];
#pragma unroll
      for (int m = 0; m < 4; ++m) {
        const int r0 = brow + wr * 64 + m * 16 + lk * 4;
#pragma unroll
        for (int j = 0; j < 4; ++j)
          ofp[(size_t)(r0 + j) * N + c] = acc[m][n][j] + bv;
      }
    }
  }
}

// Causal flash attention, swapped-QK^T 32x32x16, 8 waves/block, KVBLK=64.
// T14 async-STAGE: global_load_dwordx4 -> regs issued TWO tiles early;
// ds_write (swizzled) one tile early; raw s_barrier + lgkmcnt(0) only --
// vmcnt is NEVER drained to 0 in the loop (loads span barriers; the only
// vmcnt waits are the compiler's counted waits at the ds_write operands).
__global__ __launch_bounds__(512, 4)
void attn_causal_kernel(const u16* __restrict__ qg, const u16* __restrict__ kg_,
                        const u16* __restrict__ vT, u16* __restrict__ ob) {
  __shared__ __align__(16) u16 Kls[2][64 * 64];
  __shared__ __align__(16) u16 Vls[2][64 * 64];

  const int tid = threadIdx.x, lane = tid & 63, w = tid >> 6;  // w 0..7
  const int n = lane & 31, hi = lane >> 5;
  const int bid = blockIdx.x;
  const int bh = bid & 63;
  const int qb = (bid < 256) ? (7 - (bid >> 6)) : ((bid - 256) >> 6);
  const int q0w = qb * 256 + w * 32;
  const size_t base = (size_t)bh * 2048 * 64;
  const size_t vbase = (size_t)bh * 64 * 2048;

  // Q fragments: B-operand of mfma(K,Q): lane holds Q[q0w+n][dc*16+hi*8 .. +7]
  bf16x8 qf[4];
#pragma unroll
  for (int dc = 0; dc < 4; ++dc)
    qf[dc] = *reinterpret_cast<const bf16x8*>(
        &qg[base + (size_t)(q0w + n) * 64 + dc * 16 + hi * 8]);

  f32x16 o0 = {}, o1 = {};
  float l = 0.f;

  const int ktiles = qb * 4 + 4;  // block-uniform (>= 4)

  // reg-staging: each thread 16B K + 16B V per tile; LINEAR global reads,
  // swizzle applied at ds_write (write-side == read-side involution).
  const int krow = tid >> 3, kch = tid & 7;
  const int szr = (krow ^ (krow >> 3)) & 7;
  const u16* kgp = kg_ + base + (size_t)krow * 64 + kch * 8;
  const u16* vgp = vT + vbase + (size_t)krow * 2048 + kch * 8;
  u16* kwp = &Kls[0][krow * 64 + (kch ^ szr) * 8];
  u16* vwp = &Vls[0][krow * 64 + (kch ^ szr) * 8];

  int4 kst[2], vst[2];
  kst[0] = *reinterpret_cast<const int4*>(kgp);
  vst[0] = *reinterpret_cast<const int4*>(vgp);
  kst[1] = *reinterpret_cast<const int4*>(kgp + 4096);
  vst[1] = *reinterpret_cast<const int4*>(vgp + 64);
  *reinterpret_cast<int4*>(kwp) = kst[0];   // WR(0) -> buf 0
  *reinterpret_cast<int4*>(vwp) = vst[0];
  asm volatile("s_waitcnt lgkmcnt(0)" ::: "memory");
  __builtin_amdgcn_s_barrier();
  __builtin_amdgcn_sched_barrier(0);

  // loop-invariant read-side swizzle terms (rows n and 32+n)
  const int sw0 = ((n ^ (n >> 3)) & 7) << 4;
  const int sw1 = (((32 + n) ^ ((32 + n) >> 3)) & 7) << 4;

  for (int t = 0; t < ktiles; ++t) {
    const int k0 = t << 6;
    const int slot = t & 1;
    // LD(t+2) into the reg slot freed by WR(t) last iteration
    if (t + 2 < ktiles) {
      kst[slot] = *reinterpret_cast<const int4*>(kgp + (size_t)(t + 2) * 4096);
      vst[slot] = *reinterpret_cast<const int4*>(vgp + (t + 2) * 64);
    }
    if (k0 <= q0w) {
      const char* Kb = (const char*)&Kls[slot][0];
      const char* Vb = (const char*)&Vls[slot][0];
      const bool act1 = (k0 + 32) <= q0w;

      // ---- QK^T: both slabs, 8 MFMAs back-to-back ----
      f32x16 st0 = {}, st1 = {};
      __builtin_amdgcn_s_setprio(1);
#pragma unroll
      for (int dc = 0; dc < 4; ++dc) {
        bf16x8 kf = *reinterpret_cast<const bf16x8*>(
            Kb + n * 128 + ((((dc << 1) | hi) << 4) ^ sw0));
        st0 = __builtin_amdgcn_mfma_f32_32x32x16_bf16(kf, qf[dc], st0, 0, 0, 0);
      }
      if (act1) {
#pragma unroll
        for (int dc = 0; dc < 4; ++dc) {
          bf16x8 kf = *reinterpret_cast<const bf16x8*>(
              Kb + (32 + n) * 128 + ((((dc << 1) | hi) << 4) ^ sw1));
          st1 = __builtin_amdgcn_mfma_f32_32x32x16_bf16(kf, qf[dc], st1, 0, 0, 0);
        }
      }
      __builtin_amdgcn_s_setprio(0);

      // ---- causal mask on the diagonal slab ----
      if (k0 == q0w) {
#pragma unroll
        for (int r = 0; r < 16; ++r) {
          const int koff = (r & 3) + 8 * (r >> 2) + 4 * hi;
          if (koff > n) st0[r] = -1e30f;
        }
      }
      if (act1 && (k0 + 32) == q0w) {
#pragma unroll
        for (int r = 0; r < 16; ++r) {
          const int koff = (r & 3) + 8 * (r >> 2) + 4 * hi;
          if (koff > n) st1[r] = -1e30f;
        }
      }

      // ---- p = 2^s (log2e pre-folded into q); partial denom ----
      float rs = 0.f;
#pragma unroll
      for (int r = 0; r < 16; ++r) { st0[r] = __builtin_amdgcn_exp2f(st0[r]); rs += st0[r]; }
      if (act1) {
#pragma unroll
        for (int r = 0; r < 16; ++r) { st1[r] = __builtin_amdgcn_exp2f(st1[r]); rs += st1[r]; }
      }
      l += rs;

      // ---- pack P for both slabs, then PV MFMAs ----
      union { u32 u[4]; bf16x8 v; } pb[4];
#pragma unroll
      for (int s = 0; s < 2; ++s) {
        if (s == 1 && !act1) break;
        const f32x16& st = s ? st1 : st0;
#pragma unroll
        for (int kk = 0; kk < 2; ++kk) {
          const int gown = (kk * 2 + hi) * 4, gsnd = (kk * 2 + (hi ^ 1)) * 4;
          u32 pa0 = pk2bf(st[gown + 0], st[gown + 1]);
          u32 pa1 = pk2bf(st[gown + 2], st[gown + 3]);
          u32 ps0 = pk2bf(st[gsnd + 0], st[gsnd + 1]);
          u32 ps1 = pk2bf(st[gsnd + 2], st[gsnd + 3]);
          u32 rA = __shfl_xor(ps0, 32, 64);
          u32 rB = __shfl_xor(ps1, 32, 64);
          pb[s * 2 + kk].u[0] = hi ? rA : pa0;
          pb[s * 2 + kk].u[1] = hi ? rB : pa1;
          pb[s * 2 + kk].u[2] = hi ? pa0 : rA;
          pb[s * 2 + kk].u[3] = hi ? pa1 : rB;
        }
      }
      __builtin_amdgcn_s_setprio(1);
#pragma unroll
      for (int s = 0; s < 2; ++s) {
        if (s == 1 && !act1) break;
#pragma unroll
        for (int kk = 0; kk < 2; ++kk) {
          const int c = ((s * 4 + kk * 2 + hi) << 4);
          bf16x8 vf0 = *reinterpret_cast<const bf16x8*>(Vb + n * 128 + (c ^ sw0));
          o0 = __builtin_amdgcn_mfma_f32_32x32x16_bf16(vf0, pb[s * 2 + kk].v, o0, 0, 0, 0);
          bf16x8 vf1 = *reinterpret_cast<const bf16x8*>(Vb + (32 + n) * 128 + (c ^ sw1));
          o1 = __builtin_amdgcn_mfma_f32_32x32x16_bf16(vf1, pb[s * 2 + kk].v, o1, 0, 0, 0);
        }
      }
      __builtin_amdgcn_s_setprio(0);
    }
    // WR(t+1): compiler inserts a COUNTED vmcnt wait for kst/vst[(t+1)&1]
    if (t + 1 < ktiles) {
      const int ws = (t + 1) & 1;
      *reinterpret_cast<int4*>(kwp + ws * 4096) = kst[ws];
      *reinterpret_cast<int4*>(vwp + ws * 4096) = vst[ws];
    }
    asm volatile("s_waitcnt lgkmcnt(0)" ::: "memory");
    __builtin_amdgcn_s_barrier();
    __builtin_amdgcn_sched_barrier(0);
  }

  // ---- epilogue: O^T C-layout -> ob[b][s][h*64+d], normalize ----
  const int b = bh >> 4, h = bh & 15;
  const float lt = l + __shfl_xor(l, 32, 64);
  const float inv = 1.f / lt;
  const size_t rbase = ((size_t)(b * 2048 + q0w + n)) * 1024 + h * 64;
#pragma unroll
  for (int g = 0; g < 4; ++g) {
    ushort4 w0, w1;
    w0.x = f2bf(o0[g * 4 + 0] * inv); w0.y = f2bf(o0[g * 4 + 1] * inv);
    w0.z = f2bf(o0[g * 4 + 2] * inv); w0.w = f2bf(o0[g * 4 + 3] * inv);
    w1.x = f2bf(o1[g * 4 + 0] * inv); w1.y = f2bf(o1[g * 4 + 1] * inv);
    w1.z = f2bf(o1[g * 4 + 2] * inv); w1.w = f2bf(o1[g * 4 + 3] * inv);
    *reinterpret_cast<ushort4*>(&ob[rbase + g * 8 + hi * 4]) = w0;
    *reinterpret_cast<ushort4*>(&ob[rbase + 32 + g * 8 + hi * 4]) = w1;
  }
}

extern "C" void kernel_launch(void* const* d_in, const int* in_sizes, int n_in,
                              void* d_out, int out_size, void* d_ws, size_t ws_size,
                              hipStream_t stream) {
  const float* x     = (const float*)d_in[0];
  const float* Wqkv  = (const float*)d_in[1];
  const float* bqkv  = (const float*)d_in[2];
  const float* Wlift = (const float*)d_in[3];
  const float* blift = (const float*)d_in[4];
  float* out = (float*)d_out;

  if (ws_size < 40ull * 1024 * 1024) return;

  char* ws = (char*)d_ws;
  u16* xb     = (u16*)(ws);                        // 16 MB; reused as attn output
  u16* wqkvb  = (u16*)(ws + 16777216);             // 6 MB
  u16* wliftb = (u16*)(ws + 23068672);             // 2 MB
  u16* vT     = (u16*)(ws + 25165824);             // 16 MB
  u16* attnb  = xb;
  u16* qb = (u16*)d_out;                           // q/k in d_out (dead before lift GEMM)
  u16* kb = qb + 8388608;

  cast4_kernel<<<8192, 256, 0, stream>>>(x, xb, 2097152);
  cast4_kernel<<<3072, 256, 0, stream>>>(Wqkv, wqkvb, 786432);
  cast4_kernel<<<1024, 256, 0, stream>>>(Wlift, wliftb, 262144);

  gemm_bt_kernel<0><<<dim3(24, 64), 256, 0, stream>>>(
      xb, wqkvb, bqkv, qb, kb, vT, nullptr, 8192, 3072, 1024);

  attn_causal_kernel<<<512, 512, 0, stream>>>(qb, kb, vT, attnb);

  gemm_bt_kernel<1><<<dim3(8, 64), 256, 0, stream>>>(
      attnb, wliftb, blift, nullptr, nullptr, nullptr, out, 8192, 1024, 1024);
}

// Round 7
// 322.813 us; speedup vs baseline: 1.0052x; 1.0052x over previous
//
#include <hip/hip_runtime.h>
#include <cstdint>
#include <cstddef>

typedef unsigned short u16;
typedef unsigned int u32;
typedef __bf16 bf16x8 __attribute__((ext_vector_type(8)));
typedef float f32x4 __attribute__((ext_vector_type(4)));
typedef float f32x16 __attribute__((ext_vector_type(16)));

__device__ __forceinline__ u16 f2bf(float f) {
  unsigned u = __builtin_bit_cast(unsigned, f);
  return (u16)((u + 0x7FFFu + ((u >> 16) & 1u)) >> 16);
}

// native pack: compiler emits v_cvt_pk_bf16_f32
__device__ __forceinline__ u32 pk2bf(float lo, float hi) {
  union { __bf16 h[2]; u32 u; } t;
  t.h[0] = (__bf16)lo; t.h[1] = (__bf16)hi;
  return t.u;
}

__device__ __forceinline__ void gl_lds16(const void* g, void* l) {
  __builtin_amdgcn_global_load_lds(
      (const __attribute__((address_space(1))) unsigned int*)g,
      (__attribute__((address_space(3))) unsigned int*)l,
      16, 0, 0);
}

// fp32 -> bf16 cast, 4 elems/thread
__global__ void cast4_kernel(const float* __restrict__ in, u16* __restrict__ out, int n4) {
  int i = blockIdx.x * blockDim.x + threadIdx.x;
  if (i < n4) {
    float4 v = reinterpret_cast<const float4*>(in)[i];
    ushort4 o;
    o.x = f2bf(v.x); o.y = f2bf(v.y); o.z = f2bf(v.z); o.w = f2bf(v.w);
    reinterpret_cast<ushort4*>(out)[i] = o;
  }
}

// C = A(MxK) * B^T(NxK), bf16 operands, fp32 accum. 128x128 tile, BK=32.
template <int EPI>
__global__ __launch_bounds__(256)
void gemm_bt_kernel(const u16* __restrict__ A, const u16* __restrict__ Bw,
                    const float* __restrict__ bias,
                    u16* __restrict__ oq, u16* __restrict__ ok, u16* __restrict__ ovT,
                    float* __restrict__ ofp, int M, int N, int K) {
  __shared__ __align__(16) u16 Als[2][128 * 32];
  __shared__ __align__(16) u16 Bls[2][128 * 32];

  const int tid = threadIdx.x;
  const int lane = tid & 63;
  const int w = tid >> 6, wr = w >> 1, wc = w & 1;
  const int lr = lane & 15, lk = lane >> 4;
  const int brow = blockIdx.y * 128, bcol = blockIdx.x * 128;

  const int srow = tid >> 2;
  const int scol = (tid & 3) << 3;
  const u16* ga = A + (size_t)(brow + srow) * K + scol;
  const u16* gb = Bw + (size_t)(bcol + srow) * K + scol;

  f32x4 acc[4][4] = {};

  auto stage = [&](int buf, int kt) {
    const u16* a0 = ga + kt * 32;
    const u16* b0 = gb + kt * 32;
    gl_lds16(a0,             &Als[buf][tid * 8]);
    gl_lds16(a0 + 64 * K,    &Als[buf][2048 + tid * 8]);
    gl_lds16(b0,             &Bls[buf][tid * 8]);
    gl_lds16(b0 + 64 * K,    &Bls[buf][2048 + tid * 8]);
  };

  stage(0, 0);
  __syncthreads();

  const int nt = K >> 5;
  int cur = 0;
  for (int t = 0; t < nt; ++t) {
    if (t + 1 < nt) stage(cur ^ 1, t + 1);
    bf16x8 af[4], bfr[4];
#pragma unroll
    for (int m = 0; m < 4; ++m)
      af[m] = *reinterpret_cast<const bf16x8*>(&Als[cur][(wr * 64 + m * 16 + lr) * 32 + lk * 8]);
#pragma unroll
    for (int n = 0; n < 4; ++n)
      bfr[n] = *reinterpret_cast<const bf16x8*>(&Bls[cur][(wc * 64 + n * 16 + lr) * 32 + lk * 8]);
#pragma unroll
    for (int m = 0; m < 4; ++m)
#pragma unroll
      for (int n = 0; n < 4; ++n)
        acc[m][n] = __builtin_amdgcn_mfma_f32_16x16x32_bf16(af[m], bfr[n], acc[m][n], 0, 0, 0);
    __syncthreads();
    cur ^= 1;
  }

  if (EPI == 0) {
    const int three = bcol >> 10;
#pragma unroll
    for (int n = 0; n < 4; ++n) {
      const int c = bcol + wc * 64 + n * 16 + lr;
      const float bv = bias[c];
      const int cc = c & 1023, h = cc >> 6, hd = cc & 63;
#pragma unroll
      for (int m = 0; m < 4; ++m) {
        const int r0 = brow + wr * 64 + m * 16 + lk * 4;
        const int b = r0 >> 11;
        const int s0 = r0 & 2047;
        if (three == 2) {
          ushort4 pkv;
          pkv.x = f2bf(acc[m][n][0] + bv);
          pkv.y = f2bf(acc[m][n][1] + bv);
          pkv.z = f2bf(acc[m][n][2] + bv);
          pkv.w = f2bf(acc[m][n][3] + bv);
          *reinterpret_cast<ushort4*>(&ovT[((size_t)(b * 16 + h) * 64 + hd) * 2048 + s0]) = pkv;
        } else {
          u16* dst = (three == 0) ? oq : ok;
          // q prescale: SCALE * log2(e) so attention uses raw v_exp (2^x)
          const float sc = (three == 0) ? 0.03125f * 1.44269504089f : 1.0f;
#pragma unroll
          for (int j = 0; j < 4; ++j)
            dst[((size_t)(b * 16 + h) * 2048 + (s0 + j)) * 64 + hd] = f2bf((acc[m][n][j] + bv) * sc);
        }
      }
    }
  } else {
#pragma unroll
    for (int n = 0; n < 4; ++n) {
      const int c = bcol + wc * 64 + n * 16 + lr;
      const float bv = bias[c];
#pragma unroll
      for (int m = 0; m < 4; ++m) {
        const int r0 = brow + wr * 64 + m * 16 + lk * 4;
#pragma unroll
        for (int j = 0; j < 4; ++j)
          ofp[(size_t)(r0 + j) * N + c] = acc[m][n][j] + bv;
      }
    }
  }
}

// Causal flash attention, swapped-QK^T 32x32x16, 4 waves/block, UNIFORM WORK:
// wave owns q-tile pair (jA, 63-jA): every wave computes exactly 65 slabs,
// every block loops all 32 kv-tiles (KVBLK=64). Reg-staged K/V (named Slot
// members, rule-#20-safe), swizzled ds_write, lgkmcnt(0)+raw s_barrier only:
// prefetch loads (t+2) stay in flight across barriers (counted vmcnt).
__global__ __launch_bounds__(256, 2)
void attn_causal_kernel(const u16* __restrict__ qg, const u16* __restrict__ kg_,
                        const u16* __restrict__ vT, u16* __restrict__ ob) {
  __shared__ __align__(16) u16 Kls[2][64 * 64];
  __shared__ __align__(16) u16 Vls[2][64 * 64];

  const int tid = threadIdx.x, lane = tid & 63, w = tid >> 6;  // w 0..3
  const int n = lane & 31, hi = lane >> 5;
  const int bid = blockIdx.x;
  const int bh = bid & 63;          // all 8 blocks of a bh land on XCD bh&7
  const int bq = bid >> 6;          // 0..7
  const int jA = bq * 4 + w;        // 0..31
  const int jB = 63 - jA;           // 32..63
  const int q0A = jA * 32, q0B = jB * 32;
  const size_t base = (size_t)bh * 2048 * 64;
  const size_t vbase = (size_t)bh * 64 * 2048;

  // Q fragments (B-operand of mfma(K,Q)) for both tiles
  bf16x8 qfA[4], qfB[4];
#pragma unroll
  for (int dc = 0; dc < 4; ++dc) {
    qfA[dc] = *reinterpret_cast<const bf16x8*>(
        &qg[base + (size_t)(q0A + n) * 64 + dc * 16 + hi * 8]);
    qfB[dc] = *reinterpret_cast<const bf16x8*>(
        &qg[base + (size_t)(q0B + n) * 64 + dc * 16 + hi * 8]);
  }

  f32x16 oA0 = {}, oA1 = {}, oB0 = {}, oB1 = {};
  float lA = 0.f, lB = 0.f;

  // staging addressing: 256 thr x (2 K + 2 V) 16B chunks per tile
  const int srow_ = tid >> 2;                 // 0..63
  const int sch = tid & 3;                    // chunk 0..3 (and +4)
  const int ssz = (srow_ ^ (srow_ >> 3)) & 7;
  const u16* kgp = kg_ + base + (size_t)srow_ * 64 + sch * 8;
  const u16* vgp = vT + vbase + (size_t)srow_ * 2048 + sch * 8;
  u16* kw0 = &Kls[0][srow_ * 64 + ((sch ^ ssz) * 8)];
  u16* kw1 = &Kls[0][srow_ * 64 + (((sch + 4) ^ ssz) * 8)];
  u16* vw0 = &Vls[0][srow_ * 64 + ((sch ^ ssz) * 8)];
  u16* vw1 = &Vls[0][srow_ * 64 + (((sch + 4) ^ ssz) * 8)];

  // read-side swizzle terms (rows n and 32+n)
  const int sw0 = ((n ^ (n >> 3)) & 7) << 4;
  const int sw1 = (((32 + n) ^ ((32 + n) >> 3)) & 7) << 4;

  struct Slot { int4 k0, k1, v0, v1; };
  Slot sA, sB;

  // ---- prologue: LD(0)->sA, LD(1)->sB, WR(0)->buf0 ----
  sA.k0 = *reinterpret_cast<const int4*>(kgp);
  sA.k1 = *reinterpret_cast<const int4*>(kgp + 32);
  sA.v0 = *reinterpret_cast<const int4*>(vgp);
  sA.v1 = *reinterpret_cast<const int4*>(vgp + 32);
  sB.k0 = *reinterpret_cast<const int4*>(kgp + 4096);
  sB.k1 = *reinterpret_cast<const int4*>(kgp + 4096 + 32);
  sB.v0 = *reinterpret_cast<const int4*>(vgp + 64);
  sB.v1 = *reinterpret_cast<const int4*>(vgp + 64 + 32);
  *reinterpret_cast<int4*>(kw0) = sA.k0;
  *reinterpret_cast<int4*>(kw1) = sA.k1;
  *reinterpret_cast<int4*>(vw0) = sA.v0;
  *reinterpret_cast<int4*>(vw1) = sA.v1;
  asm volatile("s_waitcnt lgkmcnt(0)" ::: "memory");
  __builtin_amdgcn_s_barrier();
  __builtin_amdgcn_sched_barrier(0);

  // one 32-key slab: QK^T -> (mask) -> exp2 -> pack -> PV
  auto slab_one = [&](const char* Kb, const char* Vb, int s, bool diag,
                      const bf16x8 (&qf)[4], f32x16& o0, f32x16& o1, float& l) {
    const int swK = s ? sw1 : sw0;
    f32x16 st = {};
    __builtin_amdgcn_s_setprio(1);
#pragma unroll
    for (int dc = 0; dc < 4; ++dc) {
      bf16x8 kf = *reinterpret_cast<const bf16x8*>(
          Kb + (s * 32 + n) * 128 + ((((dc << 1) | hi) << 4) ^ swK));
      st = __builtin_amdgcn_mfma_f32_32x32x16_bf16(kf, qf[dc], st, 0, 0, 0);
    }
    __builtin_amdgcn_s_setprio(0);
    if (diag) {
#pragma unroll
      for (int r = 0; r < 16; ++r) {
        const int koff = (r & 3) + 8 * (r >> 2) + 4 * hi;
        if (koff > n) st[r] = -1e30f;
      }
    }
    float rs = 0.f;
#pragma unroll
    for (int r = 0; r < 16; ++r) { st[r] = __builtin_amdgcn_exp2f(st[r]); rs += st[r]; }
    l += rs;
#pragma unroll
    for (int kk = 0; kk < 2; ++kk) {
      const int gown = (kk * 2 + hi) * 4, gsnd = (kk * 2 + (hi ^ 1)) * 4;
      u32 pa0 = pk2bf(st[gown + 0], st[gown + 1]);
      u32 pa1 = pk2bf(st[gown + 2], st[gown + 3]);
      u32 ps0 = pk2bf(st[gsnd + 0], st[gsnd + 1]);
      u32 ps1 = pk2bf(st[gsnd + 2], st[gsnd + 3]);
      u32 rA = __shfl_xor(ps0, 32, 64);
      u32 rB = __shfl_xor(ps1, 32, 64);
      union { u32 u[4]; bf16x8 v; } pb;
      pb.u[0] = hi ? rA : pa0;
      pb.u[1] = hi ? rB : pa1;
      pb.u[2] = hi ? pa0 : rA;
      pb.u[3] = hi ? pa1 : rB;
      const int c = ((s * 4 + kk * 2 + hi) << 4);
      __builtin_amdgcn_s_setprio(1);
      bf16x8 vf0 = *reinterpret_cast<const bf16x8*>(Vb + n * 128 + (c ^ sw0));
      o0 = __builtin_amdgcn_mfma_f32_32x32x16_bf16(vf0, pb.v, o0, 0, 0, 0);
      bf16x8 vf1 = *reinterpret_cast<const bf16x8*>(Vb + (32 + n) * 128 + (c ^ sw1));
      o1 = __builtin_amdgcn_mfma_f32_32x32x16_bf16(vf1, pb.v, o1, 0, 0, 0);
      __builtin_amdgcn_s_setprio(0);
    }
  };

  auto tilecomp = [&](int t, const char* Kb, const char* Vb) {
#pragma unroll
    for (int s = 0; s < 2; ++s) {
      const int e = 2 * t + s;
      if (e <= jA) slab_one(Kb, Vb, s, e == jA, qfA, oA0, oA1, lA);
      if (e <= jB) slab_one(Kb, Vb, s, e == jB, qfB, oB0, oB1, lB);
    }
  };

  const char* K0 = (const char*)&Kls[0][0];
  const char* V0 = (const char*)&Vls[0][0];
  const char* K1 = (const char*)&Kls[1][0];
  const char* V1 = (const char*)&Vls[1][0];

  for (int tp = 0; tp < 16; ++tp) {
    // ---- even tile t = 2*tp: compute buf0; LD(t+2)->sA; WR(t+1): sB->buf1 ----
    {
      const int t = tp * 2;
      if (t + 2 < 32) {
        sA.k0 = *reinterpret_cast<const int4*>(kgp + (size_t)(t + 2) * 4096);
        sA.k1 = *reinterpret_cast<const int4*>(kgp + (size_t)(t + 2) * 4096 + 32);
        sA.v0 = *reinterpret_cast<const int4*>(vgp + (t + 2) * 64);
        sA.v1 = *reinterpret_cast<const int4*>(vgp + (t + 2) * 64 + 32);
      }
      tilecomp(t, K0, V0);
      *reinterpret_cast<int4*>(kw0 + 4096) = sB.k0;   // counted vmcnt here
      *reinterpret_cast<int4*>(kw1 + 4096) = sB.k1;
      *reinterpret_cast<int4*>(vw0 + 4096) = sB.v0;
      *reinterpret_cast<int4*>(vw1 + 4096) = sB.v1;
      asm volatile("s_waitcnt lgkmcnt(0)" ::: "memory");
      __builtin_amdgcn_s_barrier();
      __builtin_amdgcn_sched_barrier(0);
    }
    // ---- odd tile t = 2*tp+1: compute buf1; LD(t+2)->sB; WR(t+1): sA->buf0 ----
    {
      const int t = tp * 2 + 1;
      if (t + 2 < 32) {
        sB.k0 = *reinterpret_cast<const int4*>(kgp + (size_t)(t + 2) * 4096);
        sB.k1 = *reinterpret_cast<const int4*>(kgp + (size_t)(t + 2) * 4096 + 32);
        sB.v0 = *reinterpret_cast<const int4*>(vgp + (t + 2) * 64);
        sB.v1 = *reinterpret_cast<const int4*>(vgp + (t + 2) * 64 + 32);
      }
      tilecomp(t, K1, V1);
      if (t + 1 < 32) {
        *reinterpret_cast<int4*>(kw0) = sA.k0;
        *reinterpret_cast<int4*>(kw1) = sA.k1;
        *reinterpret_cast<int4*>(vw0) = sA.v0;
        *reinterpret_cast<int4*>(vw1) = sA.v1;
      }
      asm volatile("s_waitcnt lgkmcnt(0)" ::: "memory");
      __builtin_amdgcn_s_barrier();
      __builtin_amdgcn_sched_barrier(0);
    }
  }

  // ---- epilogue: O^T C-layout -> ob[b][s][h*64+d], normalize ----
  const int b = bh >> 4, h = bh & 15;
  auto epi = [&](int q0, const f32x16& o0, const f32x16& o1, float l) {
    const float lt = l + __shfl_xor(l, 32, 64);
    const float inv = 1.f / lt;
    const size_t rbase = ((size_t)(b * 2048 + q0 + n)) * 1024 + h * 64;
#pragma unroll
    for (int g = 0; g < 4; ++g) {
      ushort4 w0, w1;
      w0.x = f2bf(o0[g * 4 + 0] * inv); w0.y = f2bf(o0[g * 4 + 1] * inv);
      w0.z = f2bf(o0[g * 4 + 2] * inv); w0.w = f2bf(o0[g * 4 + 3] * inv);
      w1.x = f2bf(o1[g * 4 + 0] * inv); w1.y = f2bf(o1[g * 4 + 1] * inv);
      w1.z = f2bf(o1[g * 4 + 2] * inv); w1.w = f2bf(o1[g * 4 + 3] * inv);
      *reinterpret_cast<ushort4*>(&ob[rbase + g * 8 + hi * 4]) = w0;
      *reinterpret_cast<ushort4*>(&ob[rbase + 32 + g * 8 + hi * 4]) = w1;
    }
  };
  epi(q0A, oA0, oA1, lA);
  epi(q0B, oB0, oB1, lB);
}

extern "C" void kernel_launch(void* const* d_in, const int* in_sizes, int n_in,
                              void* d_out, int out_size, void* d_ws, size_t ws_size,
                              hipStream_t stream) {
  const float* x     = (const float*)d_in[0];
  const float* Wqkv  = (const float*)d_in[1];
  const float* bqkv  = (const float*)d_in[2];
  const float* Wlift = (const float*)d_in[3];
  const float* blift = (const float*)d_in[4];
  float* out = (float*)d_out;

  if (ws_size < 40ull * 1024 * 1024) return;

  char* ws = (char*)d_ws;
  u16* xb     = (u16*)(ws);                        // 16 MB; reused as attn output
  u16* wqkvb  = (u16*)(ws + 16777216);             // 6 MB
  u16* wliftb = (u16*)(ws + 23068672);             // 2 MB
  u16* vT     = (u16*)(ws + 25165824);             // 16 MB
  u16* attnb  = xb;
  u16* qb = (u16*)d_out;                           // q/k in d_out (dead before lift GEMM)
  u16* kb = qb + 8388608;

  cast4_kernel<<<8192, 256, 0, stream>>>(x, xb, 2097152);
  cast4_kernel<<<3072, 256, 0, stream>>>(Wqkv, wqkvb, 786432);
  cast4_kernel<<<1024, 256, 0, stream>>>(Wlift, wliftb, 262144);

  gemm_bt_kernel<0><<<dim3(24, 64), 256, 0, stream>>>(
      xb, wqkvb, bqkv, qb, kb, vT, nullptr, 8192, 3072, 1024);

  attn_causal_kernel<<<512, 256, 0, stream>>>(qb, kb, vT, attnb);

  gemm_bt_kernel<1><<<dim3(8, 64), 256, 0, stream>>>(
      attnb, wliftb, blift, nullptr, nullptr, nullptr, out, 8192, 1024, 1024);
}

// Round 8
// 301.371 us; speedup vs baseline: 1.0767x; 1.0712x over previous
//
#include <hip/hip_runtime.h>
#include <cstdint>
#include <cstddef>

typedef unsigned short u16;
typedef unsigned int u32;
typedef __bf16 bf16x8 __attribute__((ext_vector_type(8)));
typedef float f32x4 __attribute__((ext_vector_type(4)));
typedef float f32x16 __attribute__((ext_vector_type(16)));

__device__ __forceinline__ u16 f2bf(float f) {
  unsigned u = __builtin_bit_cast(unsigned, f);
  return (u16)((u + 0x7FFFu + ((u >> 16) & 1u)) >> 16);
}

// native pack: compiler emits v_cvt_pk_bf16_f32
__device__ __forceinline__ u32 pk2bf(float lo, float hi) {
  union { __bf16 h[2]; u32 u; } t;
  t.h[0] = (__bf16)lo; t.h[1] = (__bf16)hi;
  return t.u;
}

__device__ __forceinline__ void gl_lds16(const void* g, void* l) {
  __builtin_amdgcn_global_load_lds(
      (const __attribute__((address_space(1))) unsigned int*)g,
      (__attribute__((address_space(3))) unsigned int*)l,
      16, 0, 0);
}

// fp32 -> bf16 cast, 4 elems/thread
__global__ void cast4_kernel(const float* __restrict__ in, u16* __restrict__ out, int n4) {
  int i = blockIdx.x * blockDim.x + threadIdx.x;
  if (i < n4) {
    float4 v = reinterpret_cast<const float4*>(in)[i];
    ushort4 o;
    o.x = f2bf(v.x); o.y = f2bf(v.y); o.z = f2bf(v.z); o.w = f2bf(v.w);
    reinterpret_cast<ushort4*>(out)[i] = o;
  }
}

// C = A(MxK) * B^T(NxK), bf16 operands, fp32 accum. 128x128 tile, BK=32.
template <int EPI>
__global__ __launch_bounds__(256)
void gemm_bt_kernel(const u16* __restrict__ A, const u16* __restrict__ Bw,
                    const float* __restrict__ bias,
                    u16* __restrict__ oq, u16* __restrict__ ok, u16* __restrict__ ovT,
                    float* __restrict__ ofp, int M, int N, int K) {
  __shared__ __align__(16) u16 Als[2][128 * 32];
  __shared__ __align__(16) u16 Bls[2][128 * 32];

  const int tid = threadIdx.x;
  const int lane = tid & 63;
  const int w = tid >> 6, wr = w >> 1, wc = w & 1;
  const int lr = lane & 15, lk = lane >> 4;
  const int brow = blockIdx.y * 128, bcol = blockIdx.x * 128;

  const int srow = tid >> 2;
  const int scol = (tid & 3) << 3;
  const u16* ga = A + (size_t)(brow + srow) * K + scol;
  const u16* gb = Bw + (size_t)(bcol + srow) * K + scol;

  f32x4 acc[4][4] = {};

  auto stage = [&](int buf, int kt) {
    const u16* a0 = ga + kt * 32;
    const u16* b0 = gb + kt * 32;
    gl_lds16(a0,             &Als[buf][tid * 8]);
    gl_lds16(a0 + 64 * K,    &Als[buf][2048 + tid * 8]);
    gl_lds16(b0,             &Bls[buf][tid * 8]);
    gl_lds16(b0 + 64 * K,    &Bls[buf][2048 + tid * 8]);
  };

  stage(0, 0);
  __syncthreads();

  const int nt = K >> 5;
  int cur = 0;
  for (int t = 0; t < nt; ++t) {
    if (t + 1 < nt) stage(cur ^ 1, t + 1);
    bf16x8 af[4], bfr[4];
#pragma unroll
    for (int m = 0; m < 4; ++m)
      af[m] = *reinterpret_cast<const bf16x8*>(&Als[cur][(wr * 64 + m * 16 + lr) * 32 + lk * 8]);
#pragma unroll
    for (int n = 0; n < 4; ++n)
      bfr[n] = *reinterpret_cast<const bf16x8*>(&Bls[cur][(wc * 64 + n * 16 + lr) * 32 + lk * 8]);
#pragma unroll
    for (int m = 0; m < 4; ++m)
#pragma unroll
      for (int n = 0; n < 4; ++n)
        acc[m][n] = __builtin_amdgcn_mfma_f32_16x16x32_bf16(af[m], bfr[n], acc[m][n], 0, 0, 0);
    __syncthreads();
    cur ^= 1;
  }

  if (EPI == 0) {
    const int three = bcol >> 10;
#pragma unroll
    for (int n = 0; n < 4; ++n) {
      const int c = bcol + wc * 64 + n * 16 + lr;
      const float bv = bias[c];
      const int cc = c & 1023, h = cc >> 6, hd = cc & 63;
#pragma unroll
      for (int m = 0; m < 4; ++m) {
        const int r0 = brow + wr * 64 + m * 16 + lk * 4;
        const int b = r0 >> 11;
        const int s0 = r0 & 2047;
        if (three == 2) {
          ushort4 pkv;
          pkv.x = f2bf(acc[m][n][0] + bv);
          pkv.y = f2bf(acc[m][n][1] + bv);
          pkv.z = f2bf(acc[m][n][2] + bv);
          pkv.w = f2bf(acc[m][n][3] + bv);
          *reinterpret_cast<ushort4*>(&ovT[((size_t)(b * 16 + h) * 64 + hd) * 2048 + s0]) = pkv;
        } else {
          u16* dst = (three == 0) ? oq : ok;
          // q prescale: SCALE * log2(e) so attention uses raw v_exp (2^x)
          const float sc = (three == 0) ? 0.03125f * 1.44269504089f : 1.0f;
#pragma unroll
          for (int j = 0; j < 4; ++j)
            dst[((size_t)(b * 16 + h) * 2048 + (s0 + j)) * 64 + hd] = f2bf((acc[m][n][j] + bv) * sc);
        }
      }
    }
  } else {
#pragma unroll
    for (int n = 0; n < 4; ++n) {
      const int c = bcol + wc * 64 + n * 16 + lr;
      const float bv = bias[c];
#pragma unroll
      for (int m = 0; m < 4; ++m) {
        const int r0 = brow + wr * 64 + m * 16 + lk * 4;
#pragma unroll
        for (int j = 0; j < 4; ++j)
          ofp[(size_t)(r0 + j) * N + c] = acc[m][n][j] + bv;
      }
    }
  }
}

// Causal flash attention, swapped-QK^T 32x32x16, 2 waves/block (128 thr),
// KVBLK=32, LDS 16KB dbuf (K [32][64], V^T [64][32]), global_load_lds
// staging with pre-swizzled source (rule 21). Grid 2048 (32 qb x 64 bh),
// heavy-first LPT -> 8 blocks/CU resident, 16 waves/CU: latency hiding via
// occupancy; blocks phase independently (no cross-block convoy).
__global__ __launch_bounds__(128, 4)
void attn_causal_kernel(const u16* __restrict__ qg, const u16* __restrict__ kg_,
                        const u16* __restrict__ vT, u16* __restrict__ ob) {
  __shared__ __align__(16) u16 Kls[2][32 * 64];
  __shared__ __align__(16) u16 Vls[2][64 * 32];

  const int tid = threadIdx.x, lane = tid & 63, w = tid >> 6;  // w 0..1
  const int n = lane & 31, hi = lane >> 5;
  const int bid = blockIdx.x;
  const int bh = bid & 63;
  const int qb = 31 - (bid >> 6);          // heavy-first (LPT)
  const int q0w = qb * 64 + w * 32;
  const int jdiag = 2 * qb + w;            // this wave's diagonal slab index
  const size_t base = (size_t)bh * 2048 * 64;
  const size_t vbase = (size_t)bh * 64 * 2048;

  // Q fragments: B-operand of mfma(K,Q): lane holds Q[q0w+n][dc*16+hi*8 .. +7]
  bf16x8 qf[4];
#pragma unroll
  for (int dc = 0; dc < 4; ++dc)
    qf[dc] = *reinterpret_cast<const bf16x8*>(
        &qg[base + (size_t)(q0w + n) * 64 + dc * 16 + hi * 8]);

  f32x16 o0 = {}, o1 = {};
  float l = 0.f;

  const int ktiles = 2 * qb + 2;  // block-uniform

  // staging: K tile 4KB + V tile 4KB, 2 passes each of 128 thr x 16B.
  //   K pass p: lane covers LDS row rK = w*16+p*8+(l>>3), chunk cK = l&7
  //   V pass p: lane covers LDS row rV = w*32+p*16+(l>>2), chunk cV = l&3
  // source column chunk pre-swizzled: K ^((r^(r>>3))&7), V ^((r^(r>>2))&3)
  const int lct = tid & 63;
  const int rK0 = w * 16 + (lct >> 3), cK = lct & 7;
  const int rV0 = w * 32 + (lct >> 2), cV = lct & 3;
  const u16* kgp0 = kg_ + base + (size_t)rK0 * 64 + ((cK ^ ((rK0 ^ (rK0 >> 3)) & 7)) * 8);
  const u16* kgp1 = kg_ + base + (size_t)(rK0 + 8) * 64 + ((cK ^ (((rK0 + 8) ^ ((rK0 + 8) >> 3)) & 7)) * 8);
  const u16* vgp0 = vT + vbase + (size_t)rV0 * 2048 + ((cV ^ ((rV0 ^ (rV0 >> 2)) & 3)) * 8);
  const u16* vgp1 = vT + vbase + (size_t)(rV0 + 16) * 2048 + ((cV ^ (((rV0 + 16) ^ ((rV0 + 16) >> 2)) & 3)) * 8);
  const int dK = tid * 8 + w * 512;   // dest elem idx, +512 for pass 1
  const int dV = tid * 8 + w * 512;

  auto stage = [&](int buf, int t) {
    const size_t ko = (size_t)t * 2048;  // 32 rows * 64 elems
    gl_lds16(kgp0 + ko, &Kls[buf][dK]);
    gl_lds16(kgp1 + ko, &Kls[buf][dK + 512]);
    gl_lds16(vgp0 + t * 32, &Vls[buf][dV]);
    gl_lds16(vgp1 + t * 32, &Vls[buf][dV + 512]);
  };

  // read-side swizzle terms
  const int swk = ((n ^ (n >> 3)) & 7) << 4;              // K row n (byte)
  const int sv0 = ((n ^ (n >> 2)) & 3) << 4;              // V row n
  const int sv1 = (((32 + n) ^ ((32 + n) >> 2)) & 3) << 4; // V row 32+n

  stage(0, 0);
  __syncthreads();

  int cur = 0;
  for (int t = 0; t < ktiles; ++t) {
    if (t + 1 < ktiles) stage(cur ^ 1, t + 1);
    if (t <= jdiag) {
      const char* Kb = (const char*)&Kls[cur][0];
      const char* Vb = (const char*)&Vls[cur][0];

      // ---- QK^T: S^T[k][q], 4 MFMAs ----
      f32x16 st = {};
      __builtin_amdgcn_s_setprio(1);
#pragma unroll
      for (int dc = 0; dc < 4; ++dc) {
        bf16x8 kf = *reinterpret_cast<const bf16x8*>(
            Kb + n * 128 + ((((dc << 1) | hi) << 4) ^ swk));
        st = __builtin_amdgcn_mfma_f32_32x32x16_bf16(kf, qf[dc], st, 0, 0, 0);
      }
      __builtin_amdgcn_s_setprio(0);

      // ---- causal mask on the diagonal slab ----
      if (t == jdiag) {
#pragma unroll
        for (int r = 0; r < 16; ++r) {
          const int koff = (r & 3) + 8 * (r >> 2) + 4 * hi;
          if (koff > n) st[r] = -1e30f;
        }
      }

      // ---- p = 2^s (log2e pre-folded into q); partial denom ----
      float rs = 0.f;
#pragma unroll
      for (int r = 0; r < 16; ++r) { st[r] = __builtin_amdgcn_exp2f(st[r]); rs += st[r]; }
      l += rs;

      // ---- PV: O^T[d][q] += V^T . P^T, P repacked in-register ----
#pragma unroll
      for (int kk = 0; kk < 2; ++kk) {
        const int gown = (kk * 2 + hi) * 4, gsnd = (kk * 2 + (hi ^ 1)) * 4;
        u32 pa0 = pk2bf(st[gown + 0], st[gown + 1]);
        u32 pa1 = pk2bf(st[gown + 2], st[gown + 3]);
        u32 ps0 = pk2bf(st[gsnd + 0], st[gsnd + 1]);
        u32 ps1 = pk2bf(st[gsnd + 2], st[gsnd + 3]);
        u32 rA = __shfl_xor(ps0, 32, 64);
        u32 rB = __shfl_xor(ps1, 32, 64);
        union { u32 u[4]; bf16x8 v; } pb;
        pb.u[0] = hi ? rA : pa0;
        pb.u[1] = hi ? rB : pa1;
        pb.u[2] = hi ? pa0 : rA;
        pb.u[3] = hi ? pa1 : rB;
        const int c = ((kk * 2 + hi) << 4);
        __builtin_amdgcn_s_setprio(1);
        bf16x8 vf0 = *reinterpret_cast<const bf16x8*>(Vb + n * 64 + (c ^ sv0));
        o0 = __builtin_amdgcn_mfma_f32_32x32x16_bf16(vf0, pb.v, o0, 0, 0, 0);
        bf16x8 vf1 = *reinterpret_cast<const bf16x8*>(Vb + (32 + n) * 64 + (c ^ sv1));
        o1 = __builtin_amdgcn_mfma_f32_32x32x16_bf16(vf1, pb.v, o1, 0, 0, 0);
        __builtin_amdgcn_s_setprio(0);
      }
    }
    __syncthreads();
    cur ^= 1;
  }

  // ---- epilogue: O^T C-layout -> ob[b][s][h*64+d], normalize ----
  const int b = bh >> 4, h = bh & 15;
  const float lt = l + __shfl_xor(l, 32, 64);
  const float inv = 1.f / lt;
  const size_t rbase = ((size_t)(b * 2048 + q0w + n)) * 1024 + h * 64;
#pragma unroll
  for (int g = 0; g < 4; ++g) {
    ushort4 w0, w1;
    w0.x = f2bf(o0[g * 4 + 0] * inv); w0.y = f2bf(o0[g * 4 + 1] * inv);
    w0.z = f2bf(o0[g * 4 + 2] * inv); w0.w = f2bf(o0[g * 4 + 3] * inv);
    w1.x = f2bf(o1[g * 4 + 0] * inv); w1.y = f2bf(o1[g * 4 + 1] * inv);
    w1.z = f2bf(o1[g * 4 + 2] * inv); w1.w = f2bf(o1[g * 4 + 3] * inv);
    *reinterpret_cast<ushort4*>(&ob[rbase + g * 8 + hi * 4]) = w0;
    *reinterpret_cast<ushort4*>(&ob[rbase + 32 + g * 8 + hi * 4]) = w1;
  }
}

extern "C" void kernel_launch(void* const* d_in, const int* in_sizes, int n_in,
                              void* d_out, int out_size, void* d_ws, size_t ws_size,
                              hipStream_t stream) {
  const float* x     = (const float*)d_in[0];
  const float* Wqkv  = (const float*)d_in[1];
  const float* bqkv  = (const float*)d_in[2];
  const float* Wlift = (const float*)d_in[3];
  const float* blift = (const float*)d_in[4];
  float* out = (float*)d_out;

  if (ws_size < 40ull * 1024 * 1024) return;

  char* ws = (char*)d_ws;
  u16* xb     = (u16*)(ws);                        // 16 MB; reused as attn output
  u16* wqkvb  = (u16*)(ws + 16777216);             // 6 MB
  u16* wliftb = (u16*)(ws + 23068672);             // 2 MB
  u16* vT     = (u16*)(ws + 25165824);             // 16 MB
  u16* attnb  = xb;
  u16* qb = (u16*)d_out;                           // q/k in d_out (dead before lift GEMM)
  u16* kb = qb + 8388608;

  cast4_kernel<<<8192, 256, 0, stream>>>(x, xb, 2097152);
  cast4_kernel<<<3072, 256, 0, stream>>>(Wqkv, wqkvb, 786432);
  cast4_kernel<<<1024, 256, 0, stream>>>(Wlift, wliftb, 262144);

  gemm_bt_kernel<0><<<dim3(24, 64), 256, 0, stream>>>(
      xb, wqkvb, bqkv, qb, kb, vT, nullptr, 8192, 3072, 1024);

  attn_causal_kernel<<<2048, 128, 0, stream>>>(qb, kb, vT, attnb);

  gemm_bt_kernel<1><<<dim3(8, 64), 256, 0, stream>>>(
      attnb, wliftb, blift, nullptr, nullptr, nullptr, out, 8192, 1024, 1024);
}

// Round 9
// 295.644 us; speedup vs baseline: 1.0976x; 1.0194x over previous
//
#include <hip/hip_runtime.h>
#include <cstdint>
#include <cstddef>

typedef unsigned short u16;
typedef unsigned int u32;
typedef __bf16 bf16x8 __attribute__((ext_vector_type(8)));
typedef float f32x4 __attribute__((ext_vector_type(4)));
typedef float f32x16 __attribute__((ext_vector_type(16)));

__device__ __forceinline__ u16 f2bf(float f) {
  unsigned u = __builtin_bit_cast(unsigned, f);
  return (u16)((u + 0x7FFFu + ((u >> 16) & 1u)) >> 16);
}

// native pack: compiler emits v_cvt_pk_bf16_f32
__device__ __forceinline__ u32 pk2bf(float lo, float hi) {
  union { __bf16 h[2]; u32 u; } t;
  t.h[0] = (__bf16)lo; t.h[1] = (__bf16)hi;
  return t.u;
}

__device__ __forceinline__ void gl_lds16(const void* g, void* l) {
  __builtin_amdgcn_global_load_lds(
      (const __attribute__((address_space(1))) unsigned int*)g,
      (__attribute__((address_space(3))) unsigned int*)l,
      16, 0, 0);
}

// fp32 -> bf16 cast, 4 elems/thread
__global__ void cast4_kernel(const float* __restrict__ in, u16* __restrict__ out, int n4) {
  int i = blockIdx.x * blockDim.x + threadIdx.x;
  if (i < n4) {
    float4 v = reinterpret_cast<const float4*>(in)[i];
    ushort4 o;
    o.x = f2bf(v.x); o.y = f2bf(v.y); o.z = f2bf(v.z); o.w = f2bf(v.w);
    reinterpret_cast<ushort4*>(out)[i] = o;
  }
}

// C = A(MxK) * B^T(NxK), bf16 operands, fp32 accum. 128x128 tile, BK=32.
template <int EPI>
__global__ __launch_bounds__(256)
void gemm_bt_kernel(const u16* __restrict__ A, const u16* __restrict__ Bw,
                    const float* __restrict__ bias,
                    u16* __restrict__ oq, u16* __restrict__ ok, u16* __restrict__ ovT,
                    float* __restrict__ ofp, int M, int N, int K) {
  __shared__ __align__(16) u16 Als[2][128 * 32];
  __shared__ __align__(16) u16 Bls[2][128 * 32];

  const int tid = threadIdx.x;
  const int lane = tid & 63;
  const int w = tid >> 6, wr = w >> 1, wc = w & 1;
  const int lr = lane & 15, lk = lane >> 4;
  const int brow = blockIdx.y * 128, bcol = blockIdx.x * 128;

  const int srow = tid >> 2;
  const int scol = (tid & 3) << 3;
  const u16* ga = A + (size_t)(brow + srow) * K + scol;
  const u16* gb = Bw + (size_t)(bcol + srow) * K + scol;

  f32x4 acc[4][4] = {};

  auto stage = [&](int buf, int kt) {
    const u16* a0 = ga + kt * 32;
    const u16* b0 = gb + kt * 32;
    gl_lds16(a0,             &Als[buf][tid * 8]);
    gl_lds16(a0 + 64 * K,    &Als[buf][2048 + tid * 8]);
    gl_lds16(b0,             &Bls[buf][tid * 8]);
    gl_lds16(b0 + 64 * K,    &Bls[buf][2048 + tid * 8]);
  };

  stage(0, 0);
  __syncthreads();

  const int nt = K >> 5;
  int cur = 0;
  for (int t = 0; t < nt; ++t) {
    if (t + 1 < nt) stage(cur ^ 1, t + 1);
    bf16x8 af[4], bfr[4];
#pragma unroll
    for (int m = 0; m < 4; ++m)
      af[m] = *reinterpret_cast<const bf16x8*>(&Als[cur][(wr * 64 + m * 16 + lr) * 32 + lk * 8]);
#pragma unroll
    for (int n = 0; n < 4; ++n)
      bfr[n] = *reinterpret_cast<const bf16x8*>(&Bls[cur][(wc * 64 + n * 16 + lr) * 32 + lk * 8]);
#pragma unroll
    for (int m = 0; m < 4; ++m)
#pragma unroll
      for (int n = 0; n < 4; ++n)
        acc[m][n] = __builtin_amdgcn_mfma_f32_16x16x32_bf16(af[m], bfr[n], acc[m][n], 0, 0, 0);
    __syncthreads();
    cur ^= 1;
  }

  if (EPI == 0) {
    const int three = bcol >> 10;
#pragma unroll
    for (int n = 0; n < 4; ++n) {
      const int c = bcol + wc * 64 + n * 16 + lr;
      const float bv = bias[c];
      const int cc = c & 1023, h = cc >> 6, hd = cc & 63;
#pragma unroll
      for (int m = 0; m < 4; ++m) {
        const int r0 = brow + wr * 64 + m * 16 + lk * 4;
        const int b = r0 >> 11;
        const int s0 = r0 & 2047;
        if (three == 2) {
          ushort4 pkv;
          pkv.x = f2bf(acc[m][n][0] + bv);
          pkv.y = f2bf(acc[m][n][1] + bv);
          pkv.z = f2bf(acc[m][n][2] + bv);
          pkv.w = f2bf(acc[m][n][3] + bv);
          *reinterpret_cast<ushort4*>(&ovT[((size_t)(b * 16 + h) * 64 + hd) * 2048 + s0]) = pkv;
        } else {
          u16* dst = (three == 0) ? oq : ok;
          // q prescale: SCALE * log2(e) so attention uses raw v_exp (2^x)
          const float sc = (three == 0) ? 0.03125f * 1.44269504089f : 1.0f;
#pragma unroll
          for (int j = 0; j < 4; ++j)
            dst[((size_t)(b * 16 + h) * 2048 + (s0 + j)) * 64 + hd] = f2bf((acc[m][n][j] + bv) * sc);
        }
      }
    }
  } else {
#pragma unroll
    for (int n = 0; n < 4; ++n) {
      const int c = bcol + wc * 64 + n * 16 + lr;
      const float bv = bias[c];
#pragma unroll
      for (int m = 0; m < 4; ++m) {
        const int r0 = brow + wr * 64 + m * 16 + lk * 4;
#pragma unroll
        for (int j = 0; j < 4; ++j)
          ofp[(size_t)(r0 + j) * N + c] = acc[m][n][j] + bv;
      }
    }
  }
}

// Causal flash attention, swapped-QK^T 32x32x16, r3 structure made UNIFORM:
// 4 waves/block, each wave owns the q-tile PAIR (jA=bq*4+w, jB=63-jA); every
// block scans all 32 KV-tiles (KVBLK=64); per-wave slabs = exactly 65.
// K/V LDS fragments SHARED between the two chains (same rows -> ds_read per
// q-row halves); A/B chains independent -> 2x ILP at fixed occupancy.
// global_load_lds staging with pre-swizzled source (r3-verified, no scratch).
__global__ __launch_bounds__(256, 2)
void attn_causal_kernel(const u16* __restrict__ qg, const u16* __restrict__ kg_,
                        const u16* __restrict__ vT, u16* __restrict__ ob) {
  __shared__ __align__(16) u16 Kls[2][64 * 64];
  __shared__ __align__(16) u16 Vls[2][64 * 64];

  const int tid = threadIdx.x, lane = tid & 63, w = tid >> 6;  // w 0..3
  const int n = lane & 31, hi = lane >> 5;
  const int bid = blockIdx.x;
  const int bh = bid & 63;
  const int bq = bid >> 6;              // 0..7
  const int jA = bq * 4 + w;            // 0..31
  const int jB = 63 - jA;               // 32..63
  const int q0A = jA * 32, q0B = jB * 32;
  const size_t base = (size_t)bh * 2048 * 64;
  const size_t vbase = (size_t)bh * 64 * 2048;

  // Q fragments (B-operand of mfma(K,Q)) for both q-tiles
  bf16x8 qfA[4], qfB[4];
#pragma unroll
  for (int dc = 0; dc < 4; ++dc) {
    qfA[dc] = *reinterpret_cast<const bf16x8*>(
        &qg[base + (size_t)(q0A + n) * 64 + dc * 16 + hi * 8]);
    qfB[dc] = *reinterpret_cast<const bf16x8*>(
        &qg[base + (size_t)(q0B + n) * 64 + dc * 16 + hi * 8]);
  }

  f32x16 oA0 = {}, oA1 = {}, oB0 = {}, oB1 = {};
  float lA = 0.f, lB = 0.f;

  // staging: 2 passes x 256 lanes x 16B per operand per 64-tile (r3-verified)
  const int krow = tid >> 3, kch = tid & 7;

  auto stage = [&](int buf, int t) {
    const int k0 = t << 6;
#pragma unroll
    for (int p = 0; p < 2; ++p) {
      const int r = p * 32 + krow;
      const int sz = (r ^ (r >> 3)) & 7;
      gl_lds16(kg_ + base + (size_t)(k0 + r) * 64 + (kch ^ sz) * 8,
               &Kls[buf][p * 2048 + tid * 8]);
      gl_lds16(vT + vbase + (size_t)r * 2048 + k0 + (kch ^ sz) * 8,
               &Vls[buf][p * 2048 + tid * 8]);
    }
  };

  // loop-invariant read-side swizzle terms (rows n and 32+n)
  const int sw0 = ((n ^ (n >> 3)) & 7) << 4;
  const int sw1 = (((32 + n) ^ ((32 + n) >> 3)) & 7) << 4;

  stage(0, 0);
  __syncthreads();

  union U { u32 u[4]; bf16x8 v; };

  auto maskst = [&](f32x16& st) {
#pragma unroll
    for (int r = 0; r < 16; ++r) {
      const int koff = (r & 3) + 8 * (r >> 2) + 4 * hi;
      if (koff > n) st[r] = -1e30f;
    }
  };
  auto packp = [&](const f32x16& st, int kk, U& pb) {
    const int gown = (kk * 2 + hi) * 4, gsnd = (kk * 2 + (hi ^ 1)) * 4;
    u32 pa0 = pk2bf(st[gown + 0], st[gown + 1]);
    u32 pa1 = pk2bf(st[gown + 2], st[gown + 3]);
    u32 ps0 = pk2bf(st[gsnd + 0], st[gsnd + 1]);
    u32 ps1 = pk2bf(st[gsnd + 2], st[gsnd + 3]);
    u32 rA = __shfl_xor(ps0, 32, 64);
    u32 rB = __shfl_xor(ps1, 32, 64);
    pb.u[0] = hi ? rA : pa0;
    pb.u[1] = hi ? rB : pa1;
    pb.u[2] = hi ? pa0 : rA;
    pb.u[3] = hi ? pa1 : rB;
  };

  // one 32-key slab, serving BOTH q-chains off shared K/V fragments
  auto slab_pair = [&](const char* Kb, const char* Vb, int s,
                       bool actA, bool actB, bool diagA, bool diagB) {
    const int swK = s ? sw1 : sw0;
    bf16x8 kf[4];
#pragma unroll
    for (int dc = 0; dc < 4; ++dc)
      kf[dc] = *reinterpret_cast<const bf16x8*>(
          Kb + (s * 32 + n) * 128 + ((((dc << 1) | hi) << 4) ^ swK));
    f32x16 stA = {}, stB = {};
    __builtin_amdgcn_s_setprio(1);
#pragma unroll
    for (int dc = 0; dc < 4; ++dc) {
      if (actA) stA = __builtin_amdgcn_mfma_f32_32x32x16_bf16(kf[dc], qfA[dc], stA, 0, 0, 0);
      if (actB) stB = __builtin_amdgcn_mfma_f32_32x32x16_bf16(kf[dc], qfB[dc], stB, 0, 0, 0);
    }
    __builtin_amdgcn_s_setprio(0);
    if (diagA) maskst(stA);
    if (diagB) maskst(stB);
    if (actA) {
      float rs = 0.f;
#pragma unroll
      for (int r = 0; r < 16; ++r) { stA[r] = __builtin_amdgcn_exp2f(stA[r]); rs += stA[r]; }
      lA += rs;
    }
    if (actB) {
      float rs = 0.f;
#pragma unroll
      for (int r = 0; r < 16; ++r) { stB[r] = __builtin_amdgcn_exp2f(stB[r]); rs += stB[r]; }
      lB += rs;
    }
#pragma unroll
    for (int kk = 0; kk < 2; ++kk) {
      U pbA, pbB;
      if (actA) packp(stA, kk, pbA);
      if (actB) packp(stB, kk, pbB);
      const int c = ((s * 4 + kk * 2 + hi) << 4);
      bf16x8 vf0 = *reinterpret_cast<const bf16x8*>(Vb + n * 128 + (c ^ sw0));
      bf16x8 vf1 = *reinterpret_cast<const bf16x8*>(Vb + (32 + n) * 128 + (c ^ sw1));
      __builtin_amdgcn_s_setprio(1);
      if (actA) {
        oA0 = __builtin_amdgcn_mfma_f32_32x32x16_bf16(vf0, pbA.v, oA0, 0, 0, 0);
        oA1 = __builtin_amdgcn_mfma_f32_32x32x16_bf16(vf1, pbA.v, oA1, 0, 0, 0);
      }
      if (actB) {
        oB0 = __builtin_amdgcn_mfma_f32_32x32x16_bf16(vf0, pbB.v, oB0, 0, 0, 0);
        oB1 = __builtin_amdgcn_mfma_f32_32x32x16_bf16(vf1, pbB.v, oB1, 0, 0, 0);
      }
      __builtin_amdgcn_s_setprio(0);
    }
  };

  int cur = 0;
  for (int t = 0; t < 32; ++t) {
    if (t + 1 < 32) stage(cur ^ 1, t + 1);
    const char* Kb = (const char*)&Kls[cur][0];
    const char* Vb = (const char*)&Vls[cur][0];
#pragma unroll
    for (int s = 0; s < 2; ++s) {
      const int e = 2 * t + s;
      const bool aA = e <= jA, aB = e <= jB;
      if (aA || aB)
        slab_pair(Kb, Vb, s, aA, aB, e == jA, e == jB);
    }
    __syncthreads();
    cur ^= 1;
  }

  // ---- epilogue: O^T C-layout -> ob[b][s][h*64+d], normalize ----
  const int b = bh >> 4, h = bh & 15;
  auto epi = [&](int q0, const f32x16& o0, const f32x16& o1, float l) {
    const float lt = l + __shfl_xor(l, 32, 64);
    const float inv = 1.f / lt;
    const size_t rbase = ((size_t)(b * 2048 + q0 + n)) * 1024 + h * 64;
#pragma unroll
    for (int g = 0; g < 4; ++g) {
      ushort4 w0, w1;
      w0.x = f2bf(o0[g * 4 + 0] * inv); w0.y = f2bf(o0[g * 4 + 1] * inv);
      w0.z = f2bf(o0[g * 4 + 2] * inv); w0.w = f2bf(o0[g * 4 + 3] * inv);
      w1.x = f2bf(o1[g * 4 + 0] * inv); w1.y = f2bf(o1[g * 4 + 1] * inv);
      w1.z = f2bf(o1[g * 4 + 2] * inv); w1.w = f2bf(o1[g * 4 + 3] * inv);
      *reinterpret_cast<ushort4*>(&ob[rbase + g * 8 + hi * 4]) = w0;
      *reinterpret_cast<ushort4*>(&ob[rbase + 32 + g * 8 + hi * 4]) = w1;
    }
  };
  epi(q0A, oA0, oA1, lA);
  epi(q0B, oB0, oB1, lB);
}

extern "C" void kernel_launch(void* const* d_in, const int* in_sizes, int n_in,
                              void* d_out, int out_size, void* d_ws, size_t ws_size,
                              hipStream_t stream) {
  const float* x     = (const float*)d_in[0];
  const float* Wqkv  = (const float*)d_in[1];
  const float* bqkv  = (const float*)d_in[2];
  const float* Wlift = (const float*)d_in[3];
  const float* blift = (const float*)d_in[4];
  float* out = (float*)d_out;

  if (ws_size < 40ull * 1024 * 1024) return;

  char* ws = (char*)d_ws;
  u16* xb     = (u16*)(ws);                        // 16 MB; reused as attn output
  u16* wqkvb  = (u16*)(ws + 16777216);             // 6 MB
  u16* wliftb = (u16*)(ws + 23068672);             // 2 MB
  u16* vT     = (u16*)(ws + 25165824);             // 16 MB
  u16* attnb  = xb;
  u16* qb = (u16*)d_out;                           // q/k in d_out (dead before lift GEMM)
  u16* kb = qb + 8388608;

  cast4_kernel<<<8192, 256, 0, stream>>>(x, xb, 2097152);
  cast4_kernel<<<3072, 256, 0, stream>>>(Wqkv, wqkvb, 786432);
  cast4_kernel<<<1024, 256, 0, stream>>>(Wlift, wliftb, 262144);

  gemm_bt_kernel<0><<<dim3(24, 64), 256, 0, stream>>>(
      xb, wqkvb, bqkv, qb, kb, vT, nullptr, 8192, 3072, 1024);

  attn_causal_kernel<<<512, 256, 0, stream>>>(qb, kb, vT, attnb);

  gemm_bt_kernel<1><<<dim3(8, 64), 256, 0, stream>>>(
      attnb, wliftb, blift, nullptr, nullptr, nullptr, out, 8192, 1024, 1024);
}

// Round 10
// 268.378 us; speedup vs baseline: 1.2091x; 1.1016x over previous
//
#include <hip/hip_runtime.h>
#include <cstdint>
#include <cstddef>

typedef unsigned short u16;
typedef unsigned int u32;
typedef __bf16 bf16x8 __attribute__((ext_vector_type(8)));
typedef float f32x4 __attribute__((ext_vector_type(4)));
typedef float f32x16 __attribute__((ext_vector_type(16)));

__device__ __forceinline__ u16 f2bf(float f) {
  unsigned u = __builtin_bit_cast(unsigned, f);
  return (u16)((u + 0x7FFFu + ((u >> 16) & 1u)) >> 16);
}

// native pack: compiler emits v_cvt_pk_bf16_f32
__device__ __forceinline__ u32 pk2bf(float lo, float hi) {
  union { __bf16 h[2]; u32 u; } t;
  t.h[0] = (__bf16)lo; t.h[1] = (__bf16)hi;
  return t.u;
}

__device__ __forceinline__ void gl_lds16(const void* g, void* l) {
  __builtin_amdgcn_global_load_lds(
      (const __attribute__((address_space(1))) unsigned int*)g,
      (__attribute__((address_space(3))) unsigned int*)l,
      16, 0, 0);
}

// fp32 -> bf16 cast, 4 elems/thread
__global__ void cast4_kernel(const float* __restrict__ in, u16* __restrict__ out, int n4) {
  int i = blockIdx.x * blockDim.x + threadIdx.x;
  if (i < n4) {
    float4 v = reinterpret_cast<const float4*>(in)[i];
    ushort4 o;
    o.x = f2bf(v.x); o.y = f2bf(v.y); o.z = f2bf(v.z); o.w = f2bf(v.w);
    reinterpret_cast<ushort4*>(out)[i] = o;
  }
}

// C = A(MxK) * B^T(NxK), bf16 operands, fp32 accum. 128x128 tile, BK=32.
template <int EPI>
__global__ __launch_bounds__(256)
void gemm_bt_kernel(const u16* __restrict__ A, const u16* __restrict__ Bw,
                    const float* __restrict__ bias,
                    u16* __restrict__ oq, u16* __restrict__ ok, u16* __restrict__ ovT,
                    float* __restrict__ ofp, int M, int N, int K) {
  __shared__ __align__(16) u16 Als[2][128 * 32];
  __shared__ __align__(16) u16 Bls[2][128 * 32];

  const int tid = threadIdx.x;
  const int lane = tid & 63;
  const int w = tid >> 6, wr = w >> 1, wc = w & 1;
  const int lr = lane & 15, lk = lane >> 4;
  const int brow = blockIdx.y * 128, bcol = blockIdx.x * 128;

  const int srow = tid >> 2;
  const int scol = (tid & 3) << 3;
  const u16* ga = A + (size_t)(brow + srow) * K + scol;
  const u16* gb = Bw + (size_t)(bcol + srow) * K + scol;

  f32x4 acc[4][4] = {};

  auto stage = [&](int buf, int kt) {
    const u16* a0 = ga + kt * 32;
    const u16* b0 = gb + kt * 32;
    gl_lds16(a0,             &Als[buf][tid * 8]);
    gl_lds16(a0 + 64 * K,    &Als[buf][2048 + tid * 8]);
    gl_lds16(b0,             &Bls[buf][tid * 8]);
    gl_lds16(b0 + 64 * K,    &Bls[buf][2048 + tid * 8]);
  };

  stage(0, 0);
  __syncthreads();

  const int nt = K >> 5;
  int cur = 0;
  for (int t = 0; t < nt; ++t) {
    if (t + 1 < nt) stage(cur ^ 1, t + 1);
    bf16x8 af[4], bfr[4];
#pragma unroll
    for (int m = 0; m < 4; ++m)
      af[m] = *reinterpret_cast<const bf16x8*>(&Als[cur][(wr * 64 + m * 16 + lr) * 32 + lk * 8]);
#pragma unroll
    for (int n = 0; n < 4; ++n)
      bfr[n] = *reinterpret_cast<const bf16x8*>(&Bls[cur][(wc * 64 + n * 16 + lr) * 32 + lk * 8]);
#pragma unroll
    for (int m = 0; m < 4; ++m)
#pragma unroll
      for (int n = 0; n < 4; ++n)
        acc[m][n] = __builtin_amdgcn_mfma_f32_16x16x32_bf16(af[m], bfr[n], acc[m][n], 0, 0, 0);
    __syncthreads();
    cur ^= 1;
  }

  if (EPI == 0) {
    const int three = bcol >> 10;
#pragma unroll
    for (int n = 0; n < 4; ++n) {
      const int c = bcol + wc * 64 + n * 16 + lr;
      const float bv = bias[c];
      const int cc = c & 1023, h = cc >> 6, hd = cc & 63;
#pragma unroll
      for (int m = 0; m < 4; ++m) {
        const int r0 = brow + wr * 64 + m * 16 + lk * 4;
        const int b = r0 >> 11;
        const int s0 = r0 & 2047;
        if (three == 2) {
          ushort4 pkv;
          pkv.x = f2bf(acc[m][n][0] + bv);
          pkv.y = f2bf(acc[m][n][1] + bv);
          pkv.z = f2bf(acc[m][n][2] + bv);
          pkv.w = f2bf(acc[m][n][3] + bv);
          *reinterpret_cast<ushort4*>(&ovT[((size_t)(b * 16 + h) * 64 + hd) * 2048 + s0]) = pkv;
        } else {
          u16* dst = (three == 0) ? oq : ok;
          // q prescale: SCALE * log2(e) so attention uses raw v_exp (2^x)
          const float sc = (three == 0) ? 0.03125f * 1.44269504089f : 1.0f;
#pragma unroll
          for (int j = 0; j < 4; ++j)
            dst[((size_t)(b * 16 + h) * 2048 + (s0 + j)) * 64 + hd] = f2bf((acc[m][n][j] + bv) * sc);
        }
      }
    }
  } else {
#pragma unroll
    for (int n = 0; n < 4; ++n) {
      const int c = bcol + wc * 64 + n * 16 + lr;
      const float bv = bias[c];
#pragma unroll
      for (int m = 0; m < 4; ++m) {
        const int r0 = brow + wr * 64 + m * 16 + lk * 4;
#pragma unroll
        for (int j = 0; j < 4; ++j)
          ofp[(size_t)(r0 + j) * N + c] = acc[m][n][j] + bv;
      }
    }
  }
}

// Causal flash attention, swapped-QK^T 32x32x16, r3 base + two changes:
// (1) PV software-pipelined one slab behind (pending pb/vf in NAMED regs):
//     PV(e-1) MFMAs issue right behind QK(e) MFMAs -> PV latency + V-reads
//     leave the per-slab critical chain.
// (2) triple-buffered LDS, stage issued 2 tiles ahead (clamped dummy stages
//     keep exactly 8 loads outstanding), barrier = s_waitcnt vmcnt(4) + raw
//     s_barrier: the vmcnt(0) drain is gone; loads get ~2 rounds to land.
__global__ __launch_bounds__(256, 3)
void attn_causal_kernel(const u16* __restrict__ qg, const u16* __restrict__ kg_,
                        const u16* __restrict__ vT, u16* __restrict__ ob) {
  __shared__ __align__(16) u16 Kls[3][64 * 64];
  __shared__ __align__(16) u16 Vls[3][64 * 64];

  const int tid = threadIdx.x, lane = tid & 63, w = tid >> 6;  // w 0..3
  const int n = lane & 31, hi = lane >> 5;
  const int bid = blockIdx.x;
  const int qbi = 15 - (bid >> 6);       // heavy-first (LPT)
  const int bh = bid & 63;
  const int q0w = qbi * 128 + w * 32;
  const int jdiag = qbi * 4 + w;         // wave's diagonal slab index
  const size_t base = (size_t)bh * 2048 * 64;
  const size_t vbase = (size_t)bh * 64 * 2048;

  // Q fragments: B-operand of mfma(K,Q): lane holds Q[q0w+n][dc*16+hi*8 .. +7]
  bf16x8 qf[4];
#pragma unroll
  for (int dc = 0; dc < 4; ++dc)
    qf[dc] = *reinterpret_cast<const bf16x8*>(
        &qg[base + (size_t)(q0w + n) * 64 + dc * 16 + hi * 8]);

  f32x16 o0 = {}, o1 = {};
  float l = 0.f;

  const int ktiles = qbi * 2 + 2;

  // staging: 2 passes x 256 lanes x 16B per operand per 64-tile (r3-verified)
  const int krow = tid >> 3, kch = tid & 7;

  auto stage = [&](int buf, int t) {
    const int k0 = t << 6;
#pragma unroll
    for (int p = 0; p < 2; ++p) {
      const int r = p * 32 + krow;
      const int sz = (r ^ (r >> 3)) & 7;
      gl_lds16(kg_ + base + (size_t)(k0 + r) * 64 + (kch ^ sz) * 8,
               &Kls[buf][p * 2048 + tid * 8]);
      gl_lds16(vT + vbase + (size_t)r * 2048 + k0 + (kch ^ sz) * 8,
               &Vls[buf][p * 2048 + tid * 8]);
    }
  };

  // loop-invariant read-side swizzle terms (rows n and 32+n)
  const int sw0 = ((n ^ (n >> 3)) & 7) << 4;
  const int sw1 = (((32 + n) ^ ((32 + n) >> 3)) & 7) << 4;

  // ---- prologue: stage tiles 0,1; wait oldest 4 (tile 0) ----
  stage(0, 0);
  stage(1, ktiles > 1 ? 1 : 0);
  asm volatile("s_waitcnt vmcnt(4)" ::: "memory");
  __builtin_amdgcn_sched_barrier(0);
  __builtin_amdgcn_s_barrier();
  __builtin_amdgcn_sched_barrier(0);

  // pending-PV state: NAMED registers (rule #20)
  bf16x8 pbP0 = {}, pbP1 = {}, vfP00 = {}, vfP01 = {}, vfP10 = {}, vfP11 = {};
  bool pend = false;

  union U { u32 u[4]; bf16x8 v; };

  // one 32-key slab, PV pipelined one slab behind
  auto slab = [&](const char* Kb, const char* Vb, int mt, bool diag) {
    const int swK = mt ? sw1 : sw0;
    f32x16 st = {};
    __builtin_amdgcn_s_setprio(1);
#pragma unroll
    for (int dc = 0; dc < 4; ++dc) {
      bf16x8 kf = *reinterpret_cast<const bf16x8*>(
          Kb + (mt * 32 + n) * 128 + ((((dc << 1) | hi) << 4) ^ swK));
      st = __builtin_amdgcn_mfma_f32_32x32x16_bf16(kf, qf[dc], st, 0, 0, 0);
    }
    // pending PV of slab e-1: independent of st chain, fills MFMA pipe
    if (pend) {
      o0 = __builtin_amdgcn_mfma_f32_32x32x16_bf16(vfP00, pbP0, o0, 0, 0, 0);
      o1 = __builtin_amdgcn_mfma_f32_32x32x16_bf16(vfP01, pbP0, o1, 0, 0, 0);
      o0 = __builtin_amdgcn_mfma_f32_32x32x16_bf16(vfP10, pbP1, o0, 0, 0, 0);
      o1 = __builtin_amdgcn_mfma_f32_32x32x16_bf16(vfP11, pbP1, o1, 0, 0, 0);
    }
    __builtin_amdgcn_s_setprio(0);
    if (diag) {
#pragma unroll
      for (int r = 0; r < 16; ++r) {
        const int koff = (r & 3) + 8 * (r >> 2) + 4 * hi;
        if (koff > n) st[r] = -1e30f;
      }
    }
    float rs = 0.f;
#pragma unroll
    for (int r = 0; r < 16; ++r) { st[r] = __builtin_amdgcn_exp2f(st[r]); rs += st[r]; }
    l += rs;
    // pack this slab's P into the pending regs (pend PV already consumed old)
#pragma unroll
    for (int kk = 0; kk < 2; ++kk) {
      const int gown = (kk * 2 + hi) * 4, gsnd = (kk * 2 + (hi ^ 1)) * 4;
      u32 pa0 = pk2bf(st[gown + 0], st[gown + 1]);
      u32 pa1 = pk2bf(st[gown + 2], st[gown + 3]);
      u32 ps0 = pk2bf(st[gsnd + 0], st[gsnd + 1]);
      u32 ps1 = pk2bf(st[gsnd + 2], st[gsnd + 3]);
      u32 rA = __shfl_xor(ps0, 32, 64);
      u32 rB = __shfl_xor(ps1, 32, 64);
      U pb;
      pb.u[0] = hi ? rA : pa0;
      pb.u[1] = hi ? rB : pa1;
      pb.u[2] = hi ? pa0 : rA;
      pb.u[3] = hi ? pa1 : rB;
      if (kk == 0) pbP0 = pb.v; else pbP1 = pb.v;
    }
    // V fragments for this slab into pending regs (off the critical chain)
    const int c0 = ((mt * 4 + hi) << 4);
    const int c1 = ((mt * 4 + 2 + hi) << 4);
    vfP00 = *reinterpret_cast<const bf16x8*>(Vb + n * 128 + (c0 ^ sw0));
    vfP01 = *reinterpret_cast<const bf16x8*>(Vb + (32 + n) * 128 + (c0 ^ sw1));
    vfP10 = *reinterpret_cast<const bf16x8*>(Vb + n * 128 + (c1 ^ sw0));
    vfP11 = *reinterpret_cast<const bf16x8*>(Vb + (32 + n) * 128 + (c1 ^ sw1));
    pend = true;
  };

  for (int t = 0; t < ktiles; ++t) {
    // stage 2 ahead; clamp to last tile (dummy re-stage) so exactly 8 loads
    // are always outstanding -> vmcnt(4) is uniformly correct
    const int tpre = (t + 2 < ktiles) ? (t + 2) : (ktiles - 1);
    stage((t + 2) % 3, tpre);
    const char* Kb = (const char*)&Kls[t % 3][0];
    const char* Vb = (const char*)&Vls[t % 3][0];
    const int e0 = 2 * t;
    if (e0 <= jdiag) slab(Kb, Vb, 0, e0 == jdiag);
    if (e0 + 1 <= jdiag) slab(Kb, Vb, 1, e0 + 1 == jdiag);
    asm volatile("s_waitcnt vmcnt(4)" ::: "memory");
    __builtin_amdgcn_sched_barrier(0);
    __builtin_amdgcn_s_barrier();
    __builtin_amdgcn_sched_barrier(0);
  }

  // flush the last pending PV
  if (pend) {
    __builtin_amdgcn_s_setprio(1);
    o0 = __builtin_amdgcn_mfma_f32_32x32x16_bf16(vfP00, pbP0, o0, 0, 0, 0);
    o1 = __builtin_amdgcn_mfma_f32_32x32x16_bf16(vfP01, pbP0, o1, 0, 0, 0);
    o0 = __builtin_amdgcn_mfma_f32_32x32x16_bf16(vfP10, pbP1, o0, 0, 0, 0);
    o1 = __builtin_amdgcn_mfma_f32_32x32x16_bf16(vfP11, pbP1, o1, 0, 0, 0);
    __builtin_amdgcn_s_setprio(0);
  }

  // drain LDS-DMA before workgroup teardown (dummy stages may be in flight)
  asm volatile("s_waitcnt vmcnt(0)" ::: "memory");

  // ---- epilogue: O^T C-layout -> ob[b][s][h*64+d], normalize ----
  const int b = bh >> 4, h = bh & 15;
  const float lt = l + __shfl_xor(l, 32, 64);
  const float inv = 1.f / lt;
  const size_t rbase = ((size_t)(b * 2048 + q0w + n)) * 1024 + h * 64;
#pragma unroll
  for (int g = 0; g < 4; ++g) {
    ushort4 w0, w1;
    w0.x = f2bf(o0[g * 4 + 0] * inv); w0.y = f2bf(o0[g * 4 + 1] * inv);
    w0.z = f2bf(o0[g * 4 + 2] * inv); w0.w = f2bf(o0[g * 4 + 3] * inv);
    w1.x = f2bf(o1[g * 4 + 0] * inv); w1.y = f2bf(o1[g * 4 + 1] * inv);
    w1.z = f2bf(o1[g * 4 + 2] * inv); w1.w = f2bf(o1[g * 4 + 3] * inv);
    *reinterpret_cast<ushort4*>(&ob[rbase + g * 8 + hi * 4]) = w0;
    *reinterpret_cast<ushort4*>(&ob[rbase + 32 + g * 8 + hi * 4]) = w1;
  }
}

extern "C" void kernel_launch(void* const* d_in, const int* in_sizes, int n_in,
                              void* d_out, int out_size, void* d_ws, size_t ws_size,
                              hipStream_t stream) {
  const float* x     = (const float*)d_in[0];
  const float* Wqkv  = (const float*)d_in[1];
  const float* bqkv  = (const float*)d_in[2];
  const float* Wlift = (const float*)d_in[3];
  const float* blift = (const float*)d_in[4];
  float* out = (float*)d_out;

  if (ws_size < 40ull * 1024 * 1024) return;

  char* ws = (char*)d_ws;
  u16* xb     = (u16*)(ws);                        // 16 MB; reused as attn output
  u16* wqkvb  = (u16*)(ws + 16777216);             // 6 MB
  u16* wliftb = (u16*)(ws + 23068672);             // 2 MB
  u16* vT     = (u16*)(ws + 25165824);             // 16 MB
  u16* attnb  = xb;
  u16* qb = (u16*)d_out;                           // q/k in d_out (dead before lift GEMM)
  u16* kb = qb + 8388608;

  cast4_kernel<<<8192, 256, 0, stream>>>(x, xb, 2097152);
  cast4_kernel<<<3072, 256, 0, stream>>>(Wqkv, wqkvb, 786432);
  cast4_kernel<<<1024, 256, 0, stream>>>(Wlift, wliftb, 262144);

  gemm_bt_kernel<0><<<dim3(24, 64), 256, 0, stream>>>(
      xb, wqkvb, bqkv, qb, kb, vT, nullptr, 8192, 3072, 1024);

  attn_causal_kernel<<<1024, 256, 0, stream>>>(qb, kb, vT, attnb);

  gemm_bt_kernel<1><<<dim3(8, 64), 256, 0, stream>>>(
      attnb, wliftb, blift, nullptr, nullptr, nullptr, out, 8192, 1024, 1024);
}